// Round 12
// baseline (1096.129 us; speedup 1.0000x reference)
//
#include <hip/hip_runtime.h>
#include <hip/hip_bf16.h>
#include <stdint.h>

typedef unsigned short u16;
typedef unsigned int   u32;
typedef __attribute__((ext_vector_type(8))) short short8;
typedef __attribute__((ext_vector_type(4))) float f32x4;
typedef __attribute__((ext_vector_type(16))) float f32x16;

// ---------- bf16 helpers (storage-only bf16, f32 math) ----------
__device__ __forceinline__ float bf2f(u16 a) {
  union { u32 i; float f; } t; t.i = ((u32)a) << 16; return t.f;
}
__device__ __forceinline__ u16 f2bf(float f) {
  union { u32 i; float f; } t; t.f = f;
  u32 r = t.i + 0x7fffu + ((t.i >> 16) & 1u);   // round-nearest-even
  return (u16)(r >> 16);
}
__device__ __forceinline__ u32 pack2(float a, float b) {
  return (u32)f2bf(a) | ((u32)f2bf(b) << 16);
}
__device__ __forceinline__ void unpack8(uint4 u, float* o) {
  union { u32 i; float f; } t;
  t.i = u.x << 16;         o[0] = t.f;
  t.i = u.x & 0xffff0000u; o[1] = t.f;
  t.i = u.y << 16;         o[2] = t.f;
  t.i = u.y & 0xffff0000u; o[3] = t.f;
  t.i = u.z << 16;         o[4] = t.f;
  t.i = u.z & 0xffff0000u; o[5] = t.f;
  t.i = u.w << 16;         o[6] = t.f;
  t.i = u.w & 0xffff0000u; o[7] = t.f;
}

// async global->LDS 16B per lane; LDS dest is wave-uniform base + lane*16
__device__ __forceinline__ void gload16(const u16* g, u16* l) {
  __builtin_amdgcn_global_load_lds(
      (const __attribute__((address_space(1))) unsigned int*)g,
      (__attribute__((address_space(3))) unsigned int*)l, 16, 0, 0);
}

#define NB 4
#define NN 4600
#define FF 5
#define PP 920
#define CC 512
#define NCH 29      // ceil(920/32); chunk 28 has 24 valid keys

// ---------- weight transpose + bf16: W[512][Nc] f32 -> Wt[Nc][512] bf16 ----------
__global__ __launch_bounds__(256) void wtrans(const float* __restrict__ W,
                                              u16* __restrict__ Wt, int Nc) {
  __shared__ float tile[32][33];
  const int nb = blockIdx.x * 32, kb = blockIdx.y * 32;
  const int tx = threadIdx.x & 31, ty = threadIdx.x >> 5;
  #pragma unroll
  for (int i = 0; i < 4; i++)
    tile[ty + i * 8][tx] = W[(size_t)(kb + ty + i * 8) * Nc + nb + tx];
  __syncthreads();
  #pragma unroll
  for (int i = 0; i < 4; i++)
    Wt[(size_t)(nb + ty + i * 8) * 512 + kb + tx] = f2bf(tile[tx][ty + i * 8]);
}

// ---------- A providers ----------
struct AProvX {        // x[n,b,c] f32, row r=(b,n)
  const float* x;
  __device__ __forceinline__ void ldrow16(int r, int k0, float* o) const {
    if (r >= 18400) { for (int j = 0; j < 16; j++) o[j] = 0.f; return; }
    int b = r / NN, n = r - b * NN;
    const float* s = x + ((size_t)n * NB + b) * CC + k0;
    #pragma unroll
    for (int j = 0; j < 4; j++) {
      float4 v = *(const float4*)(s + j * 4);
      o[j * 4] = v.x; o[j * 4 + 1] = v.y; o[j * 4 + 2] = v.z; o[j * 4 + 3] = v.w;
    }
  }
};
struct AProvBF {
  const u16* a; int M;
  __device__ __forceinline__ void ldrow16(int r, int k0, float* o) const {
    if (r >= M) { for (int j = 0; j < 16; j++) o[j] = 0.f; return; }
    const u16* s = a + (size_t)r * CC + k0;
    unpack8(*(const uint4*)s, o);
    unpack8(*(const uint4*)(s + 8), o + 8);
  }
};
struct AProvDiag {
  const u16* xo;
  __device__ __forceinline__ void ldrow16(int r, int k0, float* o) const {
    if (r >= 18400) { for (int j = 0; j < 16; j++) o[j] = 0.f; return; }
    int b = r / NN, n = r - b * NN;
    int f = n / PP;
    const u16* s = xo + (((size_t)b * NN + n) * FF + f) * CC + k0;
    unpack8(*(const uint4*)s, o);
    unpack8(*(const uint4*)(s + 8), o + 8);
  }
};
struct AProvMix {
  const u16* xo; const float* attn2;
  __device__ __forceinline__ void ldrow16(int r, int k0, float* o) const {
    if (r >= 18400) { for (int j = 0; j < 16; j++) o[j] = 0.f; return; }
    int h = blockIdx.x;
    int b = r / NN, s = r - b * NN;
    const float* aw = attn2 + (((size_t)b * 8 + h) * NN + s) * FF;
    float w[5];
    #pragma unroll
    for (int f = 0; f < FF; f++) w[f] = aw[f];
    #pragma unroll
    for (int j = 0; j < 16; j++) o[j] = 0.f;
    const u16* base = xo + (size_t)r * FF * CC + k0;
    #pragma unroll
    for (int f = 0; f < FF; f++) {
      float t[16];
      const u16* s2 = base + (size_t)f * CC;
      unpack8(*(const uint4*)s2, t);
      unpack8(*(const uint4*)(s2 + 8), t + 8);
      #pragma unroll
      for (int j = 0; j < 16; j++) o[j] = fmaf(w[f], t[j], o[j]);
    }
  }
};

// ---------- C sinks ----------
struct CSinkQKV {      // q,k row-major; v chunk-blocked(32) transposed:
                       // vt[((pair*29 + p/32)*512 + c)*32 + p%32]
  u16 *q, *k, *vt;
  __device__ __forceinline__ void st(int r, int c, float val) const {
    u16 hv = f2bf(val);
    if (c < 512)        q[(size_t)r * CC + c] = hv;
    else if (c < 1024)  k[(size_t)r * CC + (c - 512)] = hv;
    else {
      int b = r / NN, n = r - b * NN;
      int f = n / PP, p = n - f * PP;
      size_t idx = (((size_t)(b * FF + f) * NCH + (p >> 5)) * 512 + (c - 1024)) * 32 + (p & 31);
      vt[idx] = hv;
    }
  }
};
struct CSinkQ2 {
  u16* o;
  __device__ __forceinline__ void st(int r, int c, float v) const {
    o[(size_t)r * CC + c] = f2bf(v * 0.125f);
  }
};
struct CSinkBF512 {
  u16* o;
  __device__ __forceinline__ void st(int r, int c, float v) const {
    o[(size_t)r * CC + c] = f2bf(v);
  }
};
struct CSinkProj {
  float* out; const float* bias;
  __device__ __forceinline__ void st(int r, int c, float v) const {
    int b = r / NN, rem = r - b * NN;
    int f = rem / PP, p = rem - f * PP;
    out[((size_t)p * (NB * FF) + b * FF + f) * CC + c] = v + bias[c];
  }
};

// ---------- MFMA GEMM, tile 128x128, 4 waves (2x2 of 64x64), BK=32, K=512 ----------
template<class AP, class CS>
__global__ __launch_bounds__(256) void mgemm128(AP ap, const u16* __restrict__ Bt,
                                                CS cs, int M) {
  __shared__ __align__(16) u16 Al[128][40];
  __shared__ __align__(16) u16 Bl[128][40];
  const int tid = threadIdx.x;
  const int wid = tid >> 6, lane = tid & 63;
  const int lr = lane & 15, lg = lane >> 4;
  const int wr = wid >> 1, wc = wid & 1;
  const int row0 = blockIdx.y * 128, col0 = blockIdx.x * 128;
  const int srow = tid >> 1, skh = tid & 1;
  f32x4 acc[4][4];
  #pragma unroll
  for (int i = 0; i < 4; i++)
    #pragma unroll
    for (int j = 0; j < 4; j++) acc[i][j] = (f32x4){0.f, 0.f, 0.f, 0.f};

  for (int k0 = 0; k0 < 512; k0 += 32) {
    __syncthreads();
    {
      float tmp[16];
      ap.ldrow16(row0 + srow, k0 + skh * 16, tmp);
      u16 tb[16];
      #pragma unroll
      for (int j = 0; j < 16; j++) tb[j] = f2bf(tmp[j]);
      *(uint4*)&Al[srow][skh * 16]     = *(const uint4*)&tb[0];
      *(uint4*)&Al[srow][skh * 16 + 8] = *(const uint4*)&tb[8];
    }
    {
      const u16* s = Bt + (size_t)(col0 + srow) * 512 + k0 + skh * 16;
      *(uint4*)&Bl[srow][skh * 16]     = *(const uint4*)s;
      *(uint4*)&Bl[srow][skh * 16 + 8] = *(const uint4*)(s + 8);
    }
    __syncthreads();
    short8 afr[4], bfr[4];
    #pragma unroll
    for (int mt = 0; mt < 4; mt++)
      afr[mt] = *(const short8*)&Al[wr * 64 + mt * 16 + lr][lg * 8];
    #pragma unroll
    for (int ct = 0; ct < 4; ct++)
      bfr[ct] = *(const short8*)&Bl[wc * 64 + ct * 16 + lr][lg * 8];
    #pragma unroll
    for (int mt = 0; mt < 4; mt++)
      #pragma unroll
      for (int ct = 0; ct < 4; ct++)
        acc[mt][ct] = __builtin_amdgcn_mfma_f32_16x16x32_bf16(afr[mt], bfr[ct], acc[mt][ct], 0, 0, 0);
  }
  #pragma unroll
  for (int mt = 0; mt < 4; mt++)
    #pragma unroll
    for (int ct = 0; ct < 4; ct++)
      #pragma unroll
      for (int r = 0; r < 4; r++) {
        int rr = row0 + wr * 64 + mt * 16 + lg * 4 + r;
        if (rr < M)
          cs.st(rr, col0 + wc * 64 + ct * 16 + lr, acc[mt][ct][r]);
      }
}

// ---------- MFMA GEMM, tile 128x64, 4 waves (4x1 of 32x64), BK=32 ----------
template<class AP, class CS>
__global__ __launch_bounds__(256) void mgemm64(AP ap, const u16* __restrict__ Bt,
                                               CS cs, int M) {
  __shared__ __align__(16) u16 Al[128][40];
  __shared__ __align__(16) u16 Bl[64][40];
  const int tid = threadIdx.x;
  const int wid = tid >> 6, lane = tid & 63;
  const int lr = lane & 15, lg = lane >> 4;
  const int row0 = blockIdx.y * 128, col0 = blockIdx.x * 64;
  const int srow = tid >> 1, skh = tid & 1;
  const int bcol = tid >> 2, bkq = tid & 3;
  f32x4 acc[2][4];
  #pragma unroll
  for (int i = 0; i < 2; i++)
    #pragma unroll
    for (int j = 0; j < 4; j++) acc[i][j] = (f32x4){0.f, 0.f, 0.f, 0.f};

  for (int k0 = 0; k0 < 512; k0 += 32) {
    __syncthreads();
    {
      float tmp[16];
      ap.ldrow16(row0 + srow, k0 + skh * 16, tmp);
      u16 tb[16];
      #pragma unroll
      for (int j = 0; j < 16; j++) tb[j] = f2bf(tmp[j]);
      *(uint4*)&Al[srow][skh * 16]     = *(const uint4*)&tb[0];
      *(uint4*)&Al[srow][skh * 16 + 8] = *(const uint4*)&tb[8];
    }
    {
      const u16* s = Bt + (size_t)(col0 + bcol) * 512 + k0 + bkq * 8;
      *(uint4*)&Bl[bcol][bkq * 8] = *(const uint4*)s;
    }
    __syncthreads();
    short8 afr[2], bfr[4];
    #pragma unroll
    for (int mt = 0; mt < 2; mt++)
      afr[mt] = *(const short8*)&Al[wid * 32 + mt * 16 + lr][lg * 8];
    #pragma unroll
    for (int ct = 0; ct < 4; ct++)
      bfr[ct] = *(const short8*)&Bl[ct * 16 + lr][lg * 8];
    #pragma unroll
    for (int mt = 0; mt < 2; mt++)
      #pragma unroll
      for (int ct = 0; ct < 4; ct++)
        acc[mt][ct] = __builtin_amdgcn_mfma_f32_16x16x32_bf16(afr[mt], bfr[ct], acc[mt][ct], 0, 0, 0);
  }
  #pragma unroll
  for (int mt = 0; mt < 2; mt++)
    #pragma unroll
    for (int ct = 0; ct < 4; ct++)
      #pragma unroll
      for (int r = 0; r < 4; r++) {
        int rr = row0 + wid * 32 + mt * 16 + lg * 4 + r;
        if (rr < M)
          cs.st(rr, col0 + ct * 16 + lr, acc[mt][ct][r]);
      }
}

// ---------- logits: k2 = xo @ Wk2, epilogue dot with q2 ----------
__global__ __launch_bounds__(256) void mgemm_logits(const u16* __restrict__ xo,
                                                    const u16* __restrict__ q2,
                                                    const u16* __restrict__ Wk2t,
                                                    float* __restrict__ attn2) {
  __shared__ __align__(16) u16 Al[128][40];
  __shared__ __align__(16) u16 Bl[128][40];
  const int tid = threadIdx.x;
  const int wid = tid >> 6, lane = tid & 63;
  const int lr = lane & 15, lg = lane >> 4;
  const int wr = wid >> 1, wc = wid & 1;
  const int row0 = blockIdx.y * 128, col0 = blockIdx.x * 128;
  const int srow = tid >> 1, skh = tid & 1;
  f32x4 acc[4][4];
  #pragma unroll
  for (int i = 0; i < 4; i++)
    #pragma unroll
    for (int j = 0; j < 4; j++) acc[i][j] = (f32x4){0.f, 0.f, 0.f, 0.f};

  for (int k0 = 0; k0 < 512; k0 += 32) {
    __syncthreads();
    {
      int r = row0 + srow;
      uint4 v0 = make_uint4(0,0,0,0), v1 = make_uint4(0,0,0,0);
      if (r < 92000) {
        const u16* s = xo + (size_t)r * CC + k0 + skh * 16;
        v0 = *(const uint4*)s; v1 = *(const uint4*)(s + 8);
      }
      *(uint4*)&Al[srow][skh * 16]     = v0;
      *(uint4*)&Al[srow][skh * 16 + 8] = v1;
    }
    {
      const u16* s = Wk2t + (size_t)(col0 + srow) * 512 + k0 + skh * 16;
      *(uint4*)&Bl[srow][skh * 16]     = *(const uint4*)s;
      *(uint4*)&Bl[srow][skh * 16 + 8] = *(const uint4*)(s + 8);
    }
    __syncthreads();
    short8 afr[4], bfr[4];
    #pragma unroll
    for (int mt = 0; mt < 4; mt++)
      afr[mt] = *(const short8*)&Al[wr * 64 + mt * 16 + lr][lg * 8];
    #pragma unroll
    for (int ct = 0; ct < 4; ct++)
      bfr[ct] = *(const short8*)&Bl[wc * 64 + ct * 16 + lr][lg * 8];
    #pragma unroll
    for (int mt = 0; mt < 4; mt++)
      #pragma unroll
      for (int ct = 0; ct < 4; ct++)
        acc[mt][ct] = __builtin_amdgcn_mfma_f32_16x16x32_bf16(afr[mt], bfr[ct], acc[mt][ct], 0, 0, 0);
  }
  const int head = blockIdx.x * 2 + wc;
  #pragma unroll
  for (int mt = 0; mt < 4; mt++) {
    float part[4] = {0.f, 0.f, 0.f, 0.f};
    #pragma unroll
    for (int r = 0; r < 4; r++) {
      int rr = row0 + wr * 64 + mt * 16 + lg * 4 + r;
      int rc = rr < 92000 ? rr : 91999;
      const u16* qrow = q2 + (size_t)(rc / 5) * CC + head * 64 + lr;
      #pragma unroll
      for (int ct = 0; ct < 4; ct++)
        part[r] = fmaf(acc[mt][ct][r], bf2f(qrow[ct * 16]), part[r]);
    }
    #pragma unroll
    for (int r = 0; r < 4; r++) {
      float v = part[r];
      v += __shfl_xor(v, 1);
      v += __shfl_xor(v, 2);
      v += __shfl_xor(v, 4);
      v += __shfl_xor(v, 8);
      int rr = row0 + wr * 64 + mt * 16 + lg * 4 + r;
      if (lr == 0 && rr < 92000) {
        int b = rr / (NN * FF), rem = rr - b * (NN * FF);
        int s = rem / FF, f = rem - s * FF;
        attn2[(((size_t)b * 8 + head) * NN + s) * FF + f] = v;
      }
    }
  }
}

// ---------- stage 1 (32x32 MFMA, ch-split QK^T, V direct from global) ----------
// Block: 4 waves = 2 q-groups x 2 ch-halves; 64 q, one (b,f), 32-key chunks.
// K LDS [32][512] dbuf (64KB, XOR unit^=(key&7)); S-exchange 16KB; V from global.
__global__ __launch_bounds__(256, 2) void stage1_mfma7(const u16* __restrict__ qg,
                                                       const u16* __restrict__ kg,
                                                       const u16* __restrict__ vt,
                                                       u16* __restrict__ xo) {
  __shared__ __align__(16) u16 KF[2][32 * 512];   // 2 x 32 KB
  __shared__ __align__(16) float Sx[4][1024];     // 16 KB, per-wave S-partial
  const int tid = threadIdx.x;
  const int wid = tid >> 6, lane = tid & 63;
  const int l31 = lane & 31, l5 = lane >> 5;
  const int qgp = wid >> 1, chh = wid & 1;
  // XCD pair-affinity remap (bijective: 1440 = 8 * 180)
  const int wgid = blockIdx.x;
  const int g = (wgid & 7) * 180 + (wgid >> 3);
  const int pair = g / 72, qt = g - pair * 72;
  const int b = pair / 5, f = pair - b * 5;
  const int q0 = qt * 64 + qgp * 32;

  const u16* kbase = kg + ((size_t)b * NN + f * PP) * CC;
  const u16* vpair = vt + (size_t)pair * NCH * 16384;   // [chunk][512 ch][32 keys]

  // ---- Q fragments (B-operand of 32x32x16): Q[q0+l31][chh*256 + cs*16 + l5*8 + j]
  short8 qf[16];
  {
    int qrow = q0 + l31; if (qrow > NN - 1) qrow = NN - 1;
    const u16* qb = qg + ((size_t)b * NN + qrow) * CC + chh * 256 + l5 * 8;
    #pragma unroll
    for (int cs = 0; cs < 16; cs++) qf[cs] = *(const short8*)(qb + cs * 16);
  }
  asm volatile("s_waitcnt vmcnt(0)" ::: "memory");

  // K staging: 8 rows/wave; row's 512ch = 64 units; lane l writes unit l,
  // content = global ch-unit (l ^ (row&7))  [involution; kk0%8==0 so key&7==row&7]
  #define STAGE_K(buf, kk0v)                                                   \
    {                                                                          \
      const int kk0_ = (kk0v);                                                 \
      _Pragma("unroll")                                                        \
      for (int c = 0; c < 8; c++) {                                            \
        int row = wid * 8 + c;                                                 \
        int key = kk0_ + row; if (key > PP - 1) key = PP - 1;                  \
        const u16* src = kbase + (size_t)key * CC + ((lane ^ (row & 7)) * 8);  \
        gload16(src, &KF[buf][row * 512]);                                     \
      }                                                                        \
    }

  STAGE_K(0, 0)

  f32x16 pacc[8];
  #pragma unroll
  for (int ct = 0; ct < 8; ct++)
    #pragma unroll
    for (int r = 0; r < 16; r++) pacc[ct][r] = 0.f;
  float m = 0.f, l = 0.f;

  float* myS = &Sx[wid][0];
  float* prS = &Sx[wid ^ 1][0];

  for (int ch = 0; ch < NCH; ch++) {         // 920 = 28*32 + 24
    const int kk0 = ch * 32;
    const int nv = (ch == NCH - 1) ? 24 : 32;
    const int cur = ch & 1, nxt = cur ^ 1;
    if (ch < NCH - 1) {
      STAGE_K(nxt, kk0 + 32)
      asm volatile("s_waitcnt vmcnt(8)" ::: "memory");
    } else {
      asm volatile("s_waitcnt vmcnt(0)" ::: "memory");
    }
    __builtin_amdgcn_s_barrier();
    __builtin_amdgcn_sched_barrier(0);
    const u16* Kb = &KF[cur][0];
    const u16* vchunk = vpair + (size_t)ch * 16384;
    // ---- QK^T-partial: 16 MFMA32 over this wave's 256-ch half ----
    f32x16 s;
    #pragma unroll
    for (int r = 0; r < 16; r++) s[r] = 0.f;
    #pragma unroll
    for (int cs = 0; cs < 16; cs++) {
      int c16 = chh * 32 + cs * 2 + l5;
      int unit = (l31 * 64) + (c16 ^ (l31 & 7));
      short8 kfr = *(const short8*)&Kb[unit * 8];
      s = __builtin_amdgcn_mfma_f32_32x32x16_bf16(kfr, qf[cs], s, 0, 0, 0);
    }
    // ---- cross-wave ch-half reduction via swizzled LDS exchange ----
    #pragma unroll
    for (int r = 0; r < 4; r++) {
      int u = lane * 4 + r;
      int su = u ^ ((u >> 3) & 3);
      f32x4 sl = (f32x4){s[4 * r], s[4 * r + 1], s[4 * r + 2], s[4 * r + 3]};
      *(f32x4*)(myS + su * 4) = sl;
    }
    asm volatile("s_waitcnt lgkmcnt(0)" ::: "memory");
    __builtin_amdgcn_s_barrier();
    __builtin_amdgcn_sched_barrier(0);
    #pragma unroll
    for (int r = 0; r < 4; r++) {
      int u = lane * 4 + r;
      int su = u ^ ((u >> 3) & 3);
      f32x4 ov = *(const f32x4*)(prS + su * 4);
      s[4 * r] += ov[0]; s[4 * r + 1] += ov[1]; s[4 * r + 2] += ov[2]; s[4 * r + 3] += ov[3];
    }
    // ---- softmax (lane owns q=l31; regs = 16 keys: (r&3)+8*(r>>2)+4*l5) ----
    float pmax = -1e30f;
    #pragma unroll
    for (int r = 0; r < 16; r++) {
      s[r] *= 0.125f;
      int key = (r & 3) + 8 * (r >> 2) + 4 * l5;
      if (key < nv) pmax = fmaxf(pmax, s[r]);
    }
    pmax = fmaxf(pmax, __shfl_xor(pmax, 32));
    if (__any(pmax - m > 8.f)) {             // deferred rescale (rare)
      float mnew = fmaxf(m, pmax);
      float rs = __expf(m - mnew);
      #pragma unroll
      for (int r = 0; r < 16; r++) {
        float rsr = __shfl(rs, (r & 3) + 8 * (r >> 2) + 4 * l5);
        #pragma unroll
        for (int ct = 0; ct < 8; ct++) pacc[ct][r] *= rsr;
      }
      l *= rs;
      m = mnew;
    }
    float P[16];
    float psum = 0.f;
    #pragma unroll
    for (int r = 0; r < 16; r++) {
      int key = (r & 3) + 8 * (r >> 2) + 4 * l5;
      P[r] = (key < nv) ? __expf(s[r] - m) : 0.f;
      psum += P[r];
    }
    psum += __shfl_xor(psum, 32);
    l += psum;
    // ---- P -> A-frags (row=q=l31, k=(l5)*8+j per 16-key window) via shfl_xor(32) ----
    u32 X0 = pack2(P[0], P[1]),  X1 = pack2(P[2], P[3]);    // keys 4h+0..3
    u32 Y0 = pack2(P[4], P[5]),  Y1 = pack2(P[6], P[7]);    // keys 8+4h..11+4h
    u32 Z0 = pack2(P[8], P[9]),  Z1 = pack2(P[10], P[11]);  // keys 16+4h..19+4h
    u32 W0 = pack2(P[12], P[13]), W1 = pack2(P[14], P[15]); // keys 24+4h..27+4h
    u32 Xs0 = __shfl_xor(X0, 32), Xs1 = __shfl_xor(X1, 32);
    u32 Ys0 = __shfl_xor(Y0, 32), Ys1 = __shfl_xor(Y1, 32);
    u32 Zs0 = __shfl_xor(Z0, 32), Zs1 = __shfl_xor(Z1, 32);
    u32 Ws0 = __shfl_xor(W0, 32), Ws1 = __shfl_xor(W1, 32);
    u32 a0[4], a1[4];
    if (l5 == 0) {
      a0[0] = X0; a0[1] = X1; a0[2] = Xs0; a0[3] = Xs1;     // keys 0-7
      a1[0] = Z0; a1[1] = Z1; a1[2] = Zs0; a1[3] = Zs1;     // keys 16-23
    } else {
      a0[0] = Ys0; a0[1] = Ys1; a0[2] = Y0; a0[3] = Y1;     // keys 8-15
      a1[0] = Ws0; a1[1] = Ws1; a1[2] = W0; a1[3] = W1;     // keys 24-31
    }
    short8 pA0 = *(const short8*)a0;
    short8 pA1 = *(const short8*)a1;
    // ---- PV: 8 ch-tiles x 2 key-windows; V direct from global (chunk-blocked) ----
    #pragma unroll
    for (int ct = 0; ct < 8; ct++) {
      const u16* vb = vchunk + (size_t)((chh * 8 + ct) * 32 + l31) * 32 + l5 * 8;
      short8 v0 = *(const short8*)vb;
      pacc[ct] = __builtin_amdgcn_mfma_f32_32x32x16_bf16(pA0, v0, pacc[ct], 0, 0, 0);
      short8 v1 = *(const short8*)(vb + 16);
      pacc[ct] = __builtin_amdgcn_mfma_f32_32x32x16_bf16(pA1, v1, pacc[ct], 0, 0, 0);
    }
    __builtin_amdgcn_s_barrier();            // all waves done with cur K / Sx
  }
  // ---- epilogue: normalize, store (wave's 256-ch half) ----
  float linv = 1.f / l;
  #pragma unroll
  for (int r = 0; r < 16; r++) {
    int qrow = (r & 3) + 8 * (r >> 2) + 4 * l5;
    float li = __shfl(linv, qrow);
    int q = q0 + qrow;
    if (q < NN) {
      size_t base = ((size_t)(b * NN + q) * FF + f) * CC + chh * 256 + l31;
      #pragma unroll
      for (int ct = 0; ct < 8; ct++)
        xo[base + ct * 32] = f2bf(pacc[ct][r] * li);
    }
  }
  #undef STAGE_K
}

// ---------- softmax over F=5, in place on attn2 ----------
__global__ __launch_bounds__(256) void softmax_f5(float* __restrict__ a) {
  int t = blockIdx.x * 256 + threadIdx.x;
  if (t >= NB * 8 * NN) return;
  float* p = a + (size_t)t * FF;
  float l0 = p[0], l1 = p[1], l2 = p[2], l3 = p[3], l4 = p[4];
  float m = fmaxf(fmaxf(fmaxf(l0, l1), fmaxf(l2, l3)), l4);
  float e0 = __expf(l0 - m), e1 = __expf(l1 - m), e2 = __expf(l2 - m),
        e3 = __expf(l3 - m), e4 = __expf(l4 - m);
  float inv = 1.f / (e0 + e1 + e2 + e3 + e4);
  p[0] = e0 * inv; p[1] = e1 * inv; p[2] = e2 * inv; p[3] = e3 * inv; p[4] = e4 * inv;
}

// ---------- sentinel ----------
__global__ void sentinel_fill(float* o) { o[threadIdx.x] = 777.0f; }

// ---------- launcher ----------
extern "C" void kernel_launch(void* const* d_in, const int* in_sizes, int n_in,
                              void* d_out, int out_size, void* d_ws, size_t ws_size,
                              hipStream_t stream) {
  const float* x     = (const float*)d_in[0];
  const float* Wqkv  = (const float*)d_in[1];
  const float* Wq2   = (const float*)d_in[2];
  const float* Wkv2  = (const float*)d_in[3];
  const float* Wproj = (const float*)d_in[4];
  const float* bproj = (const float*)d_in[5];
  float* out   = (float*)d_out;
  float* attn2 = out + (size_t)PP * NB * FF * CC;

  char* ws = (char*)d_ws;
  const size_t SZ  = (size_t)18400 * CC * 2;            // 18.8 MB
  const size_t VT2 = (size_t)20 * NCH * 16384 * 2;      // 19.0 MB (chunk-blocked-32 V)
  const size_t XO  = (size_t)92000 * CC * 2;            // 94.2 MB
  const size_t WT  = (size_t)(1536 + 512 + 1024 + 512) * 512 * 2;  // 3.67 MB
  const size_t NEED = 2 * SZ + VT2 + XO + WT;           // ~154.6 MB
  if (ws_size < NEED) {
    sentinel_fill<<<1, 256, 0, stream>>>(out);
    return;
  }
  u16* q    = (u16*)(ws);
  u16* k    = (u16*)(ws + SZ);
  u16* vt   = (u16*)(ws + 2 * SZ);
  u16* xo   = (u16*)(ws + 2 * SZ + VT2);
  u16* wt_qkv  = (u16*)(ws + 2 * SZ + VT2 + XO);
  u16* wt_q2   = wt_qkv + (size_t)1536 * 512;
  u16* wt_kv2  = wt_q2  + (size_t)512 * 512;
  u16* wt_proj = wt_kv2 + (size_t)1024 * 512;
  u16* q2   = (u16*)(ws);            // alias q (dead after stage1)
  u16* outp = (u16*)(ws + SZ);       // alias k (dead after stage1)

  // 0) weight transpose + bf16 conversion
  wtrans<<<dim3(48, 16), 256, 0, stream>>>(Wqkv,  wt_qkv,  1536);
  wtrans<<<dim3(16, 16), 256, 0, stream>>>(Wq2,   wt_q2,   512);
  wtrans<<<dim3(32, 16), 256, 0, stream>>>(Wkv2,  wt_kv2,  1024);
  wtrans<<<dim3(16, 16), 256, 0, stream>>>(Wproj, wt_proj, 512);

  // 1) QKV projection (MFMA; v written chunk-blocked-32 transposed)
  {
    AProvX ap{x}; CSinkQKV cs{q, k, vt};
    mgemm128<<<dim3(12, 144), 256, 0, stream>>>(ap, wt_qkv, cs, 18400);
  }
  // 2) stage-1 space attention (32x32 MFMA, ch-split, V-from-global) -> xo
  stage1_mfma7<<<1440, 256, 0, stream>>>(q, k, vt, xo);
  // 3) q2 = diag(xo) @ W_q2 * scale   (overwrites q region)
  {
    AProvDiag ap{xo}; CSinkQ2 cs{q2};
    mgemm128<<<dim3(4, 144), 256, 0, stream>>>(ap, wt_q2, cs, 18400);
  }
  // 4) fused k2-GEMM + q2 dot -> raw logits into attn2 slice of d_out
  mgemm_logits<<<dim3(4, 719), 256, 0, stream>>>(xo, q2, wt_kv2, attn2);
  // 5) softmax over F in place
  softmax_f5<<<(NB * 8 * NN + 255) / 256, 256, 0, stream>>>(attn2);
  // 6) fused mix + W_v2 -> out_pre (overwrites k region); BN=64, head = blockIdx.x
  {
    AProvMix ap{xo, attn2}; CSinkBF512 cs{outp};
    mgemm64<<<dim3(8, 144), 256, 0, stream>>>(ap, wt_kv2 + (size_t)512 * 512, cs, 18400);
  }
  // 7) final projection + bias + permute to (P, B*F, C)
  {
    AProvBF ap{outp, 18400}; CSinkProj cs{out, bproj};
    mgemm128<<<dim3(4, 144), 256, 0, stream>>>(ap, wt_proj, cs, 18400);
  }
}